// Round 3
// baseline (933.558 us; speedup 1.0000x reference)
//
#include <hip/hip_runtime.h>
#include <hip/hip_bf16.h>

// GCN 3-layer pipeline on MI355X.
// out = A·(relu(BN(A·(relu(BN(A·(X@W1)))@W2)))@W3) + b3
// R2: fix macro-hygiene compile error (FMA4 param 'w' clobbered '.w' member access);
//     same design as R1: spmm 8-deep gather pipeline + gemm 128x128 8x8 reg-block.

#define NPART 128

// ---------------- CSR build ----------------

__global__ void hist_k(const int* __restrict__ dst, int* __restrict__ cnt, int E) {
    int e = blockIdx.x * 256 + threadIdx.x;
    if (e < E) atomicAdd(&cnt[dst[e]], 1);
}

__global__ __launch_bounds__(1024) void scan1_k(const int* __restrict__ cnt,
                                                int* __restrict__ rowptr,
                                                int* __restrict__ bsum, int n) {
    __shared__ int wsum[16];
    int tid = threadIdx.x;
    int i0 = blockIdx.x * 2048 + tid * 2;
    int a0 = (i0 < n) ? cnt[i0] : 0;
    int a1 = (i0 + 1 < n) ? cnt[i0 + 1] : 0;
    int s = a0 + a1;
    int inc = s;
    int lane = tid & 63;
    #pragma unroll
    for (int d = 1; d < 64; d <<= 1) {
        int t = __shfl_up(inc, d);
        if (lane >= d) inc += t;
    }
    int wid = tid >> 6;
    if (lane == 63) wsum[wid] = inc;
    __syncthreads();
    if (tid < 16) {
        int v = wsum[tid];
        int iw = v;
        #pragma unroll
        for (int d = 1; d < 16; d <<= 1) {
            int t = __shfl_up(iw, d, 16);
            if (tid >= d) iw += t;
        }
        wsum[tid] = iw - v;
    }
    __syncthreads();
    int off = wsum[wid] + inc - s;
    if (i0 < n) rowptr[i0 + 1] = off + a0;
    if (i0 + 1 < n) rowptr[i0 + 2] = off + s;
    if (tid == 1023) bsum[blockIdx.x] = wsum[15] + inc;
}

__global__ void scan2_k(int* __restrict__ bsum, int nb) {
    int tid = threadIdx.x;
    int v = (tid < nb) ? bsum[tid] : 0;
    int inc = v;
    #pragma unroll
    for (int d = 1; d < 64; d <<= 1) {
        int t = __shfl_up(inc, d);
        if (tid >= d) inc += t;
    }
    if (tid < nb) bsum[tid] = inc - v;
}

__global__ void scan3_k(int* __restrict__ rowptr, int* __restrict__ cursor,
                        const int* __restrict__ bsum, int n) {
    int i = blockIdx.x * 256 + threadIdx.x;
    if (i < n) {
        int vf = rowptr[i + 1] + bsum[i >> 11];
        rowptr[i + 1] = vf;
        cursor[i + 1] = vf;
        if (i == 0) { rowptr[0] = 0; cursor[0] = 0; }
    }
}

// interleaved (col, val_bits) pairs: epair[2*p] = col, epair[2*p+1] = float bits
__global__ void fill_k(const int* __restrict__ src, const int* __restrict__ dst,
                       const float* __restrict__ ew, int* __restrict__ cursor,
                       int* __restrict__ epair, int E) {
    int e = blockIdx.x * 256 + threadIdx.x;
    if (e < E) {
        int v = dst[e];
        int p = atomicAdd(&cursor[v], 1);
        int2 pr;
        pr.x = src[e];
        pr.y = __float_as_int(ew[e]);
        *(int2*)&epair[2 * p] = pr;
    }
}

// ---------------- GEMM helpers ----------------

__device__ __forceinline__ void fma4(float4& acc, float s, const float4& vw) {
    acc.x += s * vw.x; acc.y += s * vw.y; acc.z += s * vw.z; acc.w += s * vw.w;
}

// ---------------- GEMM 128x128: Y[M x 128] = f(A[M x 128]) @ W[128 x 128] ----------------
// 256 threads, 128-row x 128-col tile, 8x8 register block per thread.

__global__ __launch_bounds__(256) void gemm128_k(
    const float* __restrict__ A, const float* __restrict__ W, float* __restrict__ Y,
    int M, const float* __restrict__ scale, const float* __restrict__ shift) {
    __shared__ float At[32][132];   // [k][row], transposed A chunk
    __shared__ float Wl[32][128];
    int tid = threadIdx.x;
    int cg = tid & 15;   // 16 col-groups x 8 cols
    int rg = tid >> 4;   // 16 row-groups x 8 rows
    int row0 = blockIdx.x * 128;

    float4 accL[8], accR[8];
    #pragma unroll
    for (int r = 0; r < 8; ++r) {
        accL[r] = make_float4(0.f, 0.f, 0.f, 0.f);
        accR[r] = make_float4(0.f, 0.f, 0.f, 0.f);
    }

    for (int kc = 0; kc < 4; ++kc) {
        #pragma unroll
        for (int t = 0; t < 4; ++t) {
            int i = tid + t * 256;
            int r = i >> 3, fc = i & 7;
            int grow = row0 + r;
            int gk = kc * 32 + fc * 4;
            float4 a = make_float4(0.f, 0.f, 0.f, 0.f);
            if (grow < M) a = *(const float4*)&A[(size_t)grow * 128 + gk];
            if (scale) {
                a.x = fmaxf(a.x * scale[gk + 0] + shift[gk + 0], 0.f);
                a.y = fmaxf(a.y * scale[gk + 1] + shift[gk + 1], 0.f);
                a.z = fmaxf(a.z * scale[gk + 2] + shift[gk + 2], 0.f);
                a.w = fmaxf(a.w * scale[gk + 3] + shift[gk + 3], 0.f);
            }
            At[fc * 4 + 0][r] = a.x;
            At[fc * 4 + 1][r] = a.y;
            At[fc * 4 + 2][r] = a.z;
            At[fc * 4 + 3][r] = a.w;
        }
        #pragma unroll
        for (int t = 0; t < 4; ++t) {
            int i = tid + t * 256;
            int k = i >> 5, c4 = i & 31;
            *(float4*)&Wl[k][c4 * 4] = *(const float4*)&W[(size_t)(kc * 32 + k) * 128 + c4 * 4];
        }
        __syncthreads();
        #pragma unroll
        for (int k = 0; k < 32; ++k) {
            float4 a0 = *(const float4*)&At[k][rg * 8];
            float4 a1 = *(const float4*)&At[k][rg * 8 + 4];
            float4 w0 = *(const float4*)&Wl[k][cg * 8];
            float4 w1 = *(const float4*)&Wl[k][cg * 8 + 4];
            fma4(accL[0], a0.x, w0); fma4(accR[0], a0.x, w1);
            fma4(accL[1], a0.y, w0); fma4(accR[1], a0.y, w1);
            fma4(accL[2], a0.z, w0); fma4(accR[2], a0.z, w1);
            fma4(accL[3], a0.w, w0); fma4(accR[3], a0.w, w1);
            fma4(accL[4], a1.x, w0); fma4(accR[4], a1.x, w1);
            fma4(accL[5], a1.y, w0); fma4(accR[5], a1.y, w1);
            fma4(accL[6], a1.z, w0); fma4(accR[6], a1.z, w1);
            fma4(accL[7], a1.w, w0); fma4(accR[7], a1.w, w1);
        }
        __syncthreads();
    }
    #pragma unroll
    for (int r = 0; r < 8; ++r) {
        int grow = row0 + rg * 8 + r;
        if (grow < M) {
            *(float4*)&Y[(size_t)grow * 128 + cg * 8] = accL[r];
            *(float4*)&Y[(size_t)grow * 128 + cg * 8 + 4] = accR[r];
        }
    }
}

// ---------------- GEMM 64-row tile for NC=40 ----------------

__global__ __launch_bounds__(256) void gemm40_k(
    const float* __restrict__ A, const float* __restrict__ W, float* __restrict__ Y,
    int M, const float* __restrict__ scale, const float* __restrict__ shift) {
    constexpr int NC = 40;
    __shared__ float At[32][68];
    __shared__ float Wl[32][NC];
    int tid = threadIdx.x;
    int cg = tid & 15;
    int rg = tid >> 4;
    int row0 = blockIdx.x * 64;

    float4 acc[4];
    #pragma unroll
    for (int r = 0; r < 4; ++r) acc[r] = make_float4(0.f, 0.f, 0.f, 0.f);

    for (int kc = 0; kc < 4; ++kc) {
        #pragma unroll
        for (int t = 0; t < 2; ++t) {
            int i = tid + t * 256;
            int r = i >> 3, fc = i & 7;
            int grow = row0 + r;
            int gk = kc * 32 + fc * 4;
            float4 a = make_float4(0.f, 0.f, 0.f, 0.f);
            if (grow < M) a = *(const float4*)&A[(size_t)grow * 128 + gk];
            a.x = fmaxf(a.x * scale[gk + 0] + shift[gk + 0], 0.f);
            a.y = fmaxf(a.y * scale[gk + 1] + shift[gk + 1], 0.f);
            a.z = fmaxf(a.z * scale[gk + 2] + shift[gk + 2], 0.f);
            a.w = fmaxf(a.w * scale[gk + 3] + shift[gk + 3], 0.f);
            At[fc * 4 + 0][r] = a.x;
            At[fc * 4 + 1][r] = a.y;
            At[fc * 4 + 2][r] = a.z;
            At[fc * 4 + 3][r] = a.w;
        }
        for (int i = tid; i < 32 * NC / 4; i += 256) {
            int k = i / (NC / 4);
            int c4 = i % (NC / 4);
            *(float4*)&Wl[k][c4 * 4] = *(const float4*)&W[(size_t)(kc * 32 + k) * NC + c4 * 4];
        }
        __syncthreads();
        if (cg * 4 < NC) {
            #pragma unroll
            for (int k = 0; k < 32; ++k) {
                float4 vw = *(const float4*)&Wl[k][cg * 4];
                float4 a = *(const float4*)&At[k][rg * 4];
                fma4(acc[0], a.x, vw);
                fma4(acc[1], a.y, vw);
                fma4(acc[2], a.z, vw);
                fma4(acc[3], a.w, vw);
            }
        }
        __syncthreads();
    }
    if (cg * 4 < NC) {
        #pragma unroll
        for (int r = 0; r < 4; ++r) {
            int grow = row0 + rg * 4 + r;
            if (grow < M) {
                *(float4*)&Y[(size_t)grow * NC + cg * 4] = acc[r];
            }
        }
    }
}

// ---------------- SpMM (gather-CSR, interleaved pairs) ----------------
// NC=128: one wave per node, float2/lane, 8-edge unrolled pipeline.

__global__ __launch_bounds__(256) void spmm128_k(
    const int* __restrict__ rowptr, const int* __restrict__ epair,
    const float* __restrict__ X, float* __restrict__ H, int n,
    float* __restrict__ psum, float* __restrict__ psq) {
    __shared__ float lsum[128];
    __shared__ float lsq[128];
    const bool doStats = (psum != nullptr);
    if (doStats) {
        for (int i = threadIdx.x; i < 128; i += 256) { lsum[i] = 0.f; lsq[i] = 0.f; }
        __syncthreads();
    }
    int lane = threadIdx.x & 63;
    int v = blockIdx.x * 4 + (threadIdx.x >> 6);
    const float2* Xr = (const float2*)X;
    const int4* ep4 = (const int4*)epair;
    if (v < n) {
        int s = rowptr[v], e = rowptr[v + 1];
        float2 acc = {0.f, 0.f};
        int i = s;
        if (i < e && (i & 1)) {  // align to even edge index for int4 pair loads
            int2 p = *(const int2*)&epair[2 * i];
            float2 x = Xr[(size_t)p.x * 64 + lane];
            float wv = __int_as_float(p.y);
            acc.x += wv * x.x; acc.y += wv * x.y;
            ++i;
        }
        int4 q0, q1, q2, q3;
        bool have = (i + 8 <= e);
        if (have) { q0 = ep4[i / 2]; q1 = ep4[i / 2 + 1]; q2 = ep4[i / 2 + 2]; q3 = ep4[i / 2 + 3]; }
        while (have) {
            int u0 = q0.x, u1 = q0.z, u2 = q1.x, u3 = q1.z;
            int u4 = q2.x, u5 = q2.z, u6 = q3.x, u7 = q3.z;
            float w0 = __int_as_float(q0.y), w1 = __int_as_float(q0.w);
            float w2 = __int_as_float(q1.y), w3 = __int_as_float(q1.w);
            float w4 = __int_as_float(q2.y), w5 = __int_as_float(q2.w);
            float w6 = __int_as_float(q3.y), w7 = __int_as_float(q3.w);
            // 8 independent gathers in flight
            float2 x0 = Xr[(size_t)u0 * 64 + lane];
            float2 x1 = Xr[(size_t)u1 * 64 + lane];
            float2 x2 = Xr[(size_t)u2 * 64 + lane];
            float2 x3 = Xr[(size_t)u3 * 64 + lane];
            float2 x4 = Xr[(size_t)u4 * 64 + lane];
            float2 x5 = Xr[(size_t)u5 * 64 + lane];
            float2 x6 = Xr[(size_t)u6 * 64 + lane];
            float2 x7 = Xr[(size_t)u7 * 64 + lane];
            i += 8;
            have = (i + 8 <= e);
            if (have) { q0 = ep4[i / 2]; q1 = ep4[i / 2 + 1]; q2 = ep4[i / 2 + 2]; q3 = ep4[i / 2 + 3]; }
            acc.x += w0 * x0.x; acc.y += w0 * x0.y;
            acc.x += w1 * x1.x; acc.y += w1 * x1.y;
            acc.x += w2 * x2.x; acc.y += w2 * x2.y;
            acc.x += w3 * x3.x; acc.y += w3 * x3.y;
            acc.x += w4 * x4.x; acc.y += w4 * x4.y;
            acc.x += w5 * x5.x; acc.y += w5 * x5.y;
            acc.x += w6 * x6.x; acc.y += w6 * x6.y;
            acc.x += w7 * x7.x; acc.y += w7 * x7.y;
        }
        for (; i + 2 <= e; i += 2) {
            int4 q = ep4[i / 2];
            float2 xa = Xr[(size_t)q.x * 64 + lane];
            float2 xb = Xr[(size_t)q.z * 64 + lane];
            float wa = __int_as_float(q.y), wb = __int_as_float(q.w);
            acc.x += wa * xa.x; acc.y += wa * xa.y;
            acc.x += wb * xb.x; acc.y += wb * xb.y;
        }
        if (i < e) {
            int2 p = *(const int2*)&epair[2 * i];
            float2 x = Xr[(size_t)p.x * 64 + lane];
            float wv = __int_as_float(p.y);
            acc.x += wv * x.x; acc.y += wv * x.y;
        }
        *(float2*)&H[(size_t)v * 128 + 2 * lane] = acc;
        if (doStats) {
            atomicAdd(&lsum[2 * lane + 0], acc.x);
            atomicAdd(&lsum[2 * lane + 1], acc.y);
            atomicAdd(&lsq[2 * lane + 0], acc.x * acc.x);
            atomicAdd(&lsq[2 * lane + 1], acc.y * acc.y);
        }
    }
    if (doStats) {
        __syncthreads();
        int p = blockIdx.x & (NPART - 1);
        for (int i = threadIdx.x; i < 128; i += 256) {
            atomicAdd(&psum[p * 128 + i], lsum[i]);
            atomicAdd(&psq[p * 128 + i], lsq[i]);
        }
    }
}

__global__ __launch_bounds__(256) void spmm40_k(
    const int* __restrict__ rowptr, const int* __restrict__ epair,
    const float* __restrict__ X, float* __restrict__ H, int n,
    const float* __restrict__ bias) {
    int lane = threadIdx.x & 63;
    int v = blockIdx.x * 4 + (threadIdx.x >> 6);
    if (v >= n) return;
    int s = rowptr[v], e = rowptr[v + 1];
    bool al = lane < 40;
    float acc = 0.f;
    int i = s;
    for (; i + 4 <= e; i += 4) {
        int2 p0 = *(const int2*)&epair[2 * i];
        int2 p1 = *(const int2*)&epair[2 * (i + 1)];
        int2 p2 = *(const int2*)&epair[2 * (i + 2)];
        int2 p3 = *(const int2*)&epair[2 * (i + 3)];
        if (al) {
            float x0 = X[(size_t)p0.x * 40 + lane];
            float x1 = X[(size_t)p1.x * 40 + lane];
            float x2 = X[(size_t)p2.x * 40 + lane];
            float x3 = X[(size_t)p3.x * 40 + lane];
            acc += __int_as_float(p0.y) * x0;
            acc += __int_as_float(p1.y) * x1;
            acc += __int_as_float(p2.y) * x2;
            acc += __int_as_float(p3.y) * x3;
        }
    }
    for (; i < e; ++i) {
        int2 p = *(const int2*)&epair[2 * i];
        if (al) acc += __int_as_float(p.y) * X[(size_t)p.x * 40 + lane];
    }
    if (al) H[(size_t)v * 40 + lane] = acc + bias[lane];
}

// ---------------- BN stats -> scale/shift ----------------

__global__ void bnstats_k(const float* __restrict__ ps, const float* __restrict__ pq,
                          const float* __restrict__ gamma, const float* __restrict__ beta,
                          float* __restrict__ scale, float* __restrict__ shift, int n) {
    int c = threadIdx.x;
    float s = 0.f, q = 0.f;
    for (int p = 0; p < NPART; ++p) {
        s += ps[p * 128 + c];
        q += pq[p * 128 + c];
    }
    float mean = s / (float)n;
    float var = q / (float)n - mean * mean;
    float sc = gamma[c] / sqrtf(var + 1e-5f);
    scale[c] = sc;
    shift[c] = beta[c] - mean * sc;
}

// ---------------- launch ----------------

extern "C" void kernel_launch(void* const* d_in, const int* in_sizes, int n_in,
                              void* d_out, int out_size, void* d_ws, size_t ws_size,
                              hipStream_t stream) {
    const float* feat = (const float*)d_in[0];
    const int* esrc   = (const int*)d_in[1];
    const int* edst   = (const int*)d_in[2];
    const float* ew   = (const float*)d_in[3];
    const float* W1   = (const float*)d_in[4];
    const float* W2   = (const float*)d_in[5];
    const float* W3   = (const float*)d_in[6];
    const float* b3   = (const float*)d_in[7];
    const float* g1   = (const float*)d_in[8];
    const float* be1  = (const float*)d_in[9];
    const float* g2   = (const float*)d_in[10];
    const float* be2  = (const float*)d_in[11];
    float* out = (float*)d_out;

    const int N = in_sizes[0] / 128;
    const int E = in_sizes[1];

    char* w = (char*)d_ws;
    size_t o = 0;
    auto alloc = [&](size_t b) { size_t r = o; o = (o + b + 255) & ~(size_t)255; return r; };
    int* rowptr   = (int*)(w + alloc((size_t)(N + 1) * 4));
    int* cursor   = (int*)(w + alloc((size_t)(N + 1) * 4));
    int* cnt      = (int*)(w + alloc((size_t)N * 4));
    int* bsum     = (int*)(w + alloc(64 * 4));
    int* epair    = (int*)(w + alloc((size_t)E * 8));
    float* stats  = (float*)(w + alloc((size_t)4 * NPART * 128 * 4));
    float* sc1    = (float*)(w + alloc(128 * 4));
    float* sh1    = (float*)(w + alloc(128 * 4));
    float* sc2    = (float*)(w + alloc(128 * 4));
    float* sh2    = (float*)(w + alloc(128 * 4));
    float* Y      = (float*)(w + alloc((size_t)N * 128 * 4));
    float* H      = (float*)(w + alloc((size_t)N * 128 * 4));
    float* p1s = stats;
    float* p1q = stats + NPART * 128;
    float* p2s = stats + 2 * NPART * 128;
    float* p2q = stats + 3 * NPART * 128;

    hipMemsetAsync(cnt, 0, (size_t)N * 4, stream);
    hipMemsetAsync(stats, 0, (size_t)4 * NPART * 128 * 4, stream);

    hist_k<<<(E + 255) / 256, 256, 0, stream>>>(edst, cnt, E);
    int nb = (N + 2047) / 2048;
    scan1_k<<<nb, 1024, 0, stream>>>(cnt, rowptr, bsum, N);
    scan2_k<<<1, 64, 0, stream>>>(bsum, nb);
    scan3_k<<<(N + 255) / 256, 256, 0, stream>>>(rowptr, cursor, bsum, N);
    fill_k<<<(E + 255) / 256, 256, 0, stream>>>(esrc, edst, ew, cursor, epair, E);

    int gb128 = (N + 127) / 128;
    int gb64 = (N + 63) / 64;
    int sb = (N + 3) / 4;

    gemm128_k<<<gb128, 256, 0, stream>>>(feat, W1, Y, N, nullptr, nullptr);
    spmm128_k<<<sb, 256, 0, stream>>>(rowptr, epair, Y, H, N, p1s, p1q);
    bnstats_k<<<1, 128, 0, stream>>>(p1s, p1q, g1, be1, sc1, sh1, N);

    gemm128_k<<<gb128, 256, 0, stream>>>(H, W2, Y, N, sc1, sh1);
    spmm128_k<<<sb, 256, 0, stream>>>(rowptr, epair, Y, H, N, p2s, p2q);
    bnstats_k<<<1, 128, 0, stream>>>(p2s, p2q, g2, be2, sc2, sh2, N);

    gemm40_k<<<gb64, 256, 0, stream>>>(H, W3, Y, N, sc2, sh2);
    spmm40_k<<<sb, 256, 0, stream>>>(rowptr, epair, Y, out, N, b3);
}

// Round 4
// 805.151 us; speedup vs baseline: 1.1595x; 1.1595x over previous
//
#include <hip/hip_runtime.h>
#include <hip/hip_bf16.h>
#include <hip/hip_fp16.h>

// GCN 3-layer pipeline on MI355X.
// out = A·(relu(BN(A·(relu(BN(A·(X@W1)))@W2)))@W3) + b3
// R4: Y1/Y2 stored fp16 (halves spmm gather bytes + gemm write bytes; fp32 accum);
//     gemm128 Wl col-split {cg*4, 64+cg*4} kills 4-way LDS bank conflict.

#define NPART 128

// ---------------- CSR build ----------------

__global__ void hist_k(const int* __restrict__ dst, int* __restrict__ cnt, int E) {
    int e = blockIdx.x * 256 + threadIdx.x;
    if (e < E) atomicAdd(&cnt[dst[e]], 1);
}

__global__ __launch_bounds__(1024) void scan1_k(const int* __restrict__ cnt,
                                                int* __restrict__ rowptr,
                                                int* __restrict__ bsum, int n) {
    __shared__ int wsum[16];
    int tid = threadIdx.x;
    int i0 = blockIdx.x * 2048 + tid * 2;
    int a0 = (i0 < n) ? cnt[i0] : 0;
    int a1 = (i0 + 1 < n) ? cnt[i0 + 1] : 0;
    int s = a0 + a1;
    int inc = s;
    int lane = tid & 63;
    #pragma unroll
    for (int d = 1; d < 64; d <<= 1) {
        int t = __shfl_up(inc, d);
        if (lane >= d) inc += t;
    }
    int wid = tid >> 6;
    if (lane == 63) wsum[wid] = inc;
    __syncthreads();
    if (tid < 16) {
        int v = wsum[tid];
        int iw = v;
        #pragma unroll
        for (int d = 1; d < 16; d <<= 1) {
            int t = __shfl_up(iw, d, 16);
            if (tid >= d) iw += t;
        }
        wsum[tid] = iw - v;
    }
    __syncthreads();
    int off = wsum[wid] + inc - s;
    if (i0 < n) rowptr[i0 + 1] = off + a0;
    if (i0 + 1 < n) rowptr[i0 + 2] = off + s;
    if (tid == 1023) bsum[blockIdx.x] = wsum[15] + inc;
}

__global__ void scan2_k(int* __restrict__ bsum, int nb) {
    int tid = threadIdx.x;
    int v = (tid < nb) ? bsum[tid] : 0;
    int inc = v;
    #pragma unroll
    for (int d = 1; d < 64; d <<= 1) {
        int t = __shfl_up(inc, d);
        if (tid >= d) inc += t;
    }
    if (tid < nb) bsum[tid] = inc - v;
}

__global__ void scan3_k(int* __restrict__ rowptr, int* __restrict__ cursor,
                        const int* __restrict__ bsum, int n) {
    int i = blockIdx.x * 256 + threadIdx.x;
    if (i < n) {
        int vf = rowptr[i + 1] + bsum[i >> 11];
        rowptr[i + 1] = vf;
        cursor[i + 1] = vf;
        if (i == 0) { rowptr[0] = 0; cursor[0] = 0; }
    }
}

// interleaved (col, val_bits) pairs
__global__ void fill_k(const int* __restrict__ src, const int* __restrict__ dst,
                       const float* __restrict__ ew, int* __restrict__ cursor,
                       int* __restrict__ epair, int E) {
    int e = blockIdx.x * 256 + threadIdx.x;
    if (e < E) {
        int v = dst[e];
        int p = atomicAdd(&cursor[v], 1);
        int2 pr;
        pr.x = src[e];
        pr.y = __float_as_int(ew[e]);
        *(int2*)&epair[2 * p] = pr;
    }
}

// ---------------- GEMM helpers ----------------

__device__ __forceinline__ void fma4(float4& acc, float s, const float4& vw) {
    acc.x += s * vw.x; acc.y += s * vw.y; acc.z += s * vw.z; acc.w += s * vw.w;
}

// ---------------- GEMM 128x128 -> fp16 out ----------------
// 256 threads, 128x128 tile, 8x8 reg block; thread cols = {cg*4..+3, 64+cg*4..+3}
// (16 B col stride -> 2-way LDS aliasing, free; cg*8 was 4-way).

__global__ __launch_bounds__(256) void gemm128_k(
    const float* __restrict__ A, const float* __restrict__ W, __half* __restrict__ Yh,
    int M, const float* __restrict__ scale, const float* __restrict__ shift) {
    __shared__ float At[32][132];   // [k][row]
    __shared__ float Wl[32][128];
    int tid = threadIdx.x;
    int cg = tid & 15;
    int rg = tid >> 4;
    int row0 = blockIdx.x * 128;

    float4 accL[8], accR[8];
    #pragma unroll
    for (int r = 0; r < 8; ++r) {
        accL[r] = make_float4(0.f, 0.f, 0.f, 0.f);
        accR[r] = make_float4(0.f, 0.f, 0.f, 0.f);
    }

    for (int kc = 0; kc < 4; ++kc) {
        #pragma unroll
        for (int t = 0; t < 4; ++t) {
            int i = tid + t * 256;
            int r = i >> 3, fc = i & 7;
            int grow = row0 + r;
            int gk = kc * 32 + fc * 4;
            float4 a = make_float4(0.f, 0.f, 0.f, 0.f);
            if (grow < M) a = *(const float4*)&A[(size_t)grow * 128 + gk];
            if (scale) {
                a.x = fmaxf(a.x * scale[gk + 0] + shift[gk + 0], 0.f);
                a.y = fmaxf(a.y * scale[gk + 1] + shift[gk + 1], 0.f);
                a.z = fmaxf(a.z * scale[gk + 2] + shift[gk + 2], 0.f);
                a.w = fmaxf(a.w * scale[gk + 3] + shift[gk + 3], 0.f);
            }
            At[fc * 4 + 0][r] = a.x;
            At[fc * 4 + 1][r] = a.y;
            At[fc * 4 + 2][r] = a.z;
            At[fc * 4 + 3][r] = a.w;
        }
        #pragma unroll
        for (int t = 0; t < 4; ++t) {
            int i = tid + t * 256;
            int k = i >> 5, c4 = i & 31;
            *(float4*)&Wl[k][c4 * 4] = *(const float4*)&W[(size_t)(kc * 32 + k) * 128 + c4 * 4];
        }
        __syncthreads();
        #pragma unroll
        for (int k = 0; k < 32; ++k) {
            float4 a0 = *(const float4*)&At[k][rg * 8];
            float4 a1 = *(const float4*)&At[k][rg * 8 + 4];
            float4 w0 = *(const float4*)&Wl[k][cg * 4];
            float4 w1 = *(const float4*)&Wl[k][64 + cg * 4];
            fma4(accL[0], a0.x, w0); fma4(accR[0], a0.x, w1);
            fma4(accL[1], a0.y, w0); fma4(accR[1], a0.y, w1);
            fma4(accL[2], a0.z, w0); fma4(accR[2], a0.z, w1);
            fma4(accL[3], a0.w, w0); fma4(accR[3], a0.w, w1);
            fma4(accL[4], a1.x, w0); fma4(accR[4], a1.x, w1);
            fma4(accL[5], a1.y, w0); fma4(accR[5], a1.y, w1);
            fma4(accL[6], a1.z, w0); fma4(accR[6], a1.z, w1);
            fma4(accL[7], a1.w, w0); fma4(accR[7], a1.w, w1);
        }
        __syncthreads();
    }
    #pragma unroll
    for (int r = 0; r < 8; ++r) {
        int grow = row0 + rg * 8 + r;
        if (grow < M) {
            __half2 l01 = __floats2half2_rn(accL[r].x, accL[r].y);
            __half2 l23 = __floats2half2_rn(accL[r].z, accL[r].w);
            __half2 r01 = __floats2half2_rn(accR[r].x, accR[r].y);
            __half2 r23 = __floats2half2_rn(accR[r].z, accR[r].w);
            *(__half2*)&Yh[(size_t)grow * 128 + cg * 4 + 0] = l01;
            *(__half2*)&Yh[(size_t)grow * 128 + cg * 4 + 2] = l23;
            *(__half2*)&Yh[(size_t)grow * 128 + 64 + cg * 4 + 0] = r01;
            *(__half2*)&Yh[(size_t)grow * 128 + 64 + cg * 4 + 2] = r23;
        }
    }
}

// ---------------- GEMM 64-row tile for NC=40 (fp32 in/out) ----------------

__global__ __launch_bounds__(256) void gemm40_k(
    const float* __restrict__ A, const float* __restrict__ W, float* __restrict__ Y,
    int M, const float* __restrict__ scale, const float* __restrict__ shift) {
    constexpr int NC = 40;
    __shared__ float At[32][68];
    __shared__ float Wl[32][NC];
    int tid = threadIdx.x;
    int cg = tid & 15;
    int rg = tid >> 4;
    int row0 = blockIdx.x * 64;

    float4 acc[4];
    #pragma unroll
    for (int r = 0; r < 4; ++r) acc[r] = make_float4(0.f, 0.f, 0.f, 0.f);

    for (int kc = 0; kc < 4; ++kc) {
        #pragma unroll
        for (int t = 0; t < 2; ++t) {
            int i = tid + t * 256;
            int r = i >> 3, fc = i & 7;
            int grow = row0 + r;
            int gk = kc * 32 + fc * 4;
            float4 a = make_float4(0.f, 0.f, 0.f, 0.f);
            if (grow < M) a = *(const float4*)&A[(size_t)grow * 128 + gk];
            a.x = fmaxf(a.x * scale[gk + 0] + shift[gk + 0], 0.f);
            a.y = fmaxf(a.y * scale[gk + 1] + shift[gk + 1], 0.f);
            a.z = fmaxf(a.z * scale[gk + 2] + shift[gk + 2], 0.f);
            a.w = fmaxf(a.w * scale[gk + 3] + shift[gk + 3], 0.f);
            At[fc * 4 + 0][r] = a.x;
            At[fc * 4 + 1][r] = a.y;
            At[fc * 4 + 2][r] = a.z;
            At[fc * 4 + 3][r] = a.w;
        }
        for (int i = tid; i < 32 * NC / 4; i += 256) {
            int k = i / (NC / 4);
            int c4 = i % (NC / 4);
            *(float4*)&Wl[k][c4 * 4] = *(const float4*)&W[(size_t)(kc * 32 + k) * NC + c4 * 4];
        }
        __syncthreads();
        if (cg * 4 < NC) {
            #pragma unroll
            for (int k = 0; k < 32; ++k) {
                float4 vw = *(const float4*)&Wl[k][cg * 4];
                float4 a = *(const float4*)&At[k][rg * 4];
                fma4(acc[0], a.x, vw);
                fma4(acc[1], a.y, vw);
                fma4(acc[2], a.z, vw);
                fma4(acc[3], a.w, vw);
            }
        }
        __syncthreads();
    }
    if (cg * 4 < NC) {
        #pragma unroll
        for (int r = 0; r < 4; ++r) {
            int grow = row0 + rg * 4 + r;
            if (grow < M) {
                *(float4*)&Y[(size_t)grow * NC + cg * 4] = acc[r];
            }
        }
    }
}

// ---------------- SpMM 128ch from fp16 X ----------------
// One wave per node; 2 fp16 channels per lane; fp32 accumulate; fp32 H out.

__global__ __launch_bounds__(256) void spmm128_k(
    const int* __restrict__ rowptr, const int* __restrict__ epair,
    const __half* __restrict__ X, float* __restrict__ H, int n,
    float* __restrict__ psum, float* __restrict__ psq) {
    __shared__ float lsum[128];
    __shared__ float lsq[128];
    const bool doStats = (psum != nullptr);
    if (doStats) {
        for (int i = threadIdx.x; i < 128; i += 256) { lsum[i] = 0.f; lsq[i] = 0.f; }
        __syncthreads();
    }
    int lane = threadIdx.x & 63;
    int v = blockIdx.x * 4 + (threadIdx.x >> 6);
    const __half2* X2 = (const __half2*)X;
    const int4* ep4 = (const int4*)epair;
    if (v < n) {
        int s = rowptr[v], e = rowptr[v + 1];
        float2 acc = {0.f, 0.f};
        int i = s;
        if (i < e && (i & 1)) {
            int2 p = *(const int2*)&epair[2 * i];
            float2 x = __half22float2(X2[(size_t)p.x * 64 + lane]);
            float wv = __int_as_float(p.y);
            acc.x += wv * x.x; acc.y += wv * x.y;
            ++i;
        }
        int4 q0, q1, q2, q3;
        bool have = (i + 8 <= e);
        if (have) { q0 = ep4[i / 2]; q1 = ep4[i / 2 + 1]; q2 = ep4[i / 2 + 2]; q3 = ep4[i / 2 + 3]; }
        while (have) {
            int u0 = q0.x, u1 = q0.z, u2 = q1.x, u3 = q1.z;
            int u4 = q2.x, u5 = q2.z, u6 = q3.x, u7 = q3.z;
            float w0 = __int_as_float(q0.y), w1 = __int_as_float(q0.w);
            float w2 = __int_as_float(q1.y), w3 = __int_as_float(q1.w);
            float w4 = __int_as_float(q2.y), w5 = __int_as_float(q2.w);
            float w6 = __int_as_float(q3.y), w7 = __int_as_float(q3.w);
            __half2 h0 = X2[(size_t)u0 * 64 + lane];
            __half2 h1 = X2[(size_t)u1 * 64 + lane];
            __half2 h2 = X2[(size_t)u2 * 64 + lane];
            __half2 h3 = X2[(size_t)u3 * 64 + lane];
            __half2 h4 = X2[(size_t)u4 * 64 + lane];
            __half2 h5 = X2[(size_t)u5 * 64 + lane];
            __half2 h6 = X2[(size_t)u6 * 64 + lane];
            __half2 h7 = X2[(size_t)u7 * 64 + lane];
            i += 8;
            have = (i + 8 <= e);
            if (have) { q0 = ep4[i / 2]; q1 = ep4[i / 2 + 1]; q2 = ep4[i / 2 + 2]; q3 = ep4[i / 2 + 3]; }
            float2 x0 = __half22float2(h0);
            float2 x1 = __half22float2(h1);
            float2 x2 = __half22float2(h2);
            float2 x3 = __half22float2(h3);
            float2 x4 = __half22float2(h4);
            float2 x5 = __half22float2(h5);
            float2 x6 = __half22float2(h6);
            float2 x7 = __half22float2(h7);
            acc.x += w0 * x0.x; acc.y += w0 * x0.y;
            acc.x += w1 * x1.x; acc.y += w1 * x1.y;
            acc.x += w2 * x2.x; acc.y += w2 * x2.y;
            acc.x += w3 * x3.x; acc.y += w3 * x3.y;
            acc.x += w4 * x4.x; acc.y += w4 * x4.y;
            acc.x += w5 * x5.x; acc.y += w5 * x5.y;
            acc.x += w6 * x6.x; acc.y += w6 * x6.y;
            acc.x += w7 * x7.x; acc.y += w7 * x7.y;
        }
        for (; i + 2 <= e; i += 2) {
            int4 q = ep4[i / 2];
            float2 xa = __half22float2(X2[(size_t)q.x * 64 + lane]);
            float2 xb = __half22float2(X2[(size_t)q.z * 64 + lane]);
            float wa = __int_as_float(q.y), wb = __int_as_float(q.w);
            acc.x += wa * xa.x; acc.y += wa * xa.y;
            acc.x += wb * xb.x; acc.y += wb * xb.y;
        }
        if (i < e) {
            int2 p = *(const int2*)&epair[2 * i];
            float2 x = __half22float2(X2[(size_t)p.x * 64 + lane]);
            float wv = __int_as_float(p.y);
            acc.x += wv * x.x; acc.y += wv * x.y;
        }
        *(float2*)&H[(size_t)v * 128 + 2 * lane] = acc;
        if (doStats) {
            atomicAdd(&lsum[2 * lane + 0], acc.x);
            atomicAdd(&lsum[2 * lane + 1], acc.y);
            atomicAdd(&lsq[2 * lane + 0], acc.x * acc.x);
            atomicAdd(&lsq[2 * lane + 1], acc.y * acc.y);
        }
    }
    if (doStats) {
        __syncthreads();
        int p = blockIdx.x & (NPART - 1);
        for (int i = threadIdx.x; i < 128; i += 256) {
            atomicAdd(&psum[p * 128 + i], lsum[i]);
            atomicAdd(&psq[p * 128 + i], lsq[i]);
        }
    }
}

__global__ __launch_bounds__(256) void spmm40_k(
    const int* __restrict__ rowptr, const int* __restrict__ epair,
    const float* __restrict__ X, float* __restrict__ H, int n,
    const float* __restrict__ bias) {
    int lane = threadIdx.x & 63;
    int v = blockIdx.x * 4 + (threadIdx.x >> 6);
    if (v >= n) return;
    int s = rowptr[v], e = rowptr[v + 1];
    bool al = lane < 40;
    float acc = 0.f;
    int i = s;
    for (; i + 4 <= e; i += 4) {
        int2 p0 = *(const int2*)&epair[2 * i];
        int2 p1 = *(const int2*)&epair[2 * (i + 1)];
        int2 p2 = *(const int2*)&epair[2 * (i + 2)];
        int2 p3 = *(const int2*)&epair[2 * (i + 3)];
        if (al) {
            float x0 = X[(size_t)p0.x * 40 + lane];
            float x1 = X[(size_t)p1.x * 40 + lane];
            float x2 = X[(size_t)p2.x * 40 + lane];
            float x3 = X[(size_t)p3.x * 40 + lane];
            acc += __int_as_float(p0.y) * x0;
            acc += __int_as_float(p1.y) * x1;
            acc += __int_as_float(p2.y) * x2;
            acc += __int_as_float(p3.y) * x3;
        }
    }
    for (; i < e; ++i) {
        int2 p = *(const int2*)&epair[2 * i];
        if (al) acc += __int_as_float(p.y) * X[(size_t)p.x * 40 + lane];
    }
    if (al) H[(size_t)v * 40 + lane] = acc + bias[lane];
}

// ---------------- BN stats -> scale/shift ----------------

__global__ void bnstats_k(const float* __restrict__ ps, const float* __restrict__ pq,
                          const float* __restrict__ gamma, const float* __restrict__ beta,
                          float* __restrict__ scale, float* __restrict__ shift, int n) {
    int c = threadIdx.x;
    float s = 0.f, q = 0.f;
    for (int p = 0; p < NPART; ++p) {
        s += ps[p * 128 + c];
        q += pq[p * 128 + c];
    }
    float mean = s / (float)n;
    float var = q / (float)n - mean * mean;
    float sc = gamma[c] / sqrtf(var + 1e-5f);
    scale[c] = sc;
    shift[c] = beta[c] - mean * sc;
}

// ---------------- launch ----------------

extern "C" void kernel_launch(void* const* d_in, const int* in_sizes, int n_in,
                              void* d_out, int out_size, void* d_ws, size_t ws_size,
                              hipStream_t stream) {
    const float* feat = (const float*)d_in[0];
    const int* esrc   = (const int*)d_in[1];
    const int* edst   = (const int*)d_in[2];
    const float* ew   = (const float*)d_in[3];
    const float* W1   = (const float*)d_in[4];
    const float* W2   = (const float*)d_in[5];
    const float* W3   = (const float*)d_in[6];
    const float* b3   = (const float*)d_in[7];
    const float* g1   = (const float*)d_in[8];
    const float* be1  = (const float*)d_in[9];
    const float* g2   = (const float*)d_in[10];
    const float* be2  = (const float*)d_in[11];
    float* out = (float*)d_out;

    const int N = in_sizes[0] / 128;
    const int E = in_sizes[1];

    char* w = (char*)d_ws;
    size_t o = 0;
    auto alloc = [&](size_t b) { size_t r = o; o = (o + b + 255) & ~(size_t)255; return r; };
    int* rowptr   = (int*)(w + alloc((size_t)(N + 1) * 4));
    int* cursor   = (int*)(w + alloc((size_t)(N + 1) * 4));
    int* cnt      = (int*)(w + alloc((size_t)N * 4));
    int* bsum     = (int*)(w + alloc(64 * 4));
    int* epair    = (int*)(w + alloc((size_t)E * 8));
    float* stats  = (float*)(w + alloc((size_t)4 * NPART * 128 * 4));
    float* sc1    = (float*)(w + alloc(128 * 4));
    float* sh1    = (float*)(w + alloc(128 * 4));
    float* sc2    = (float*)(w + alloc(128 * 4));
    float* sh2    = (float*)(w + alloc(128 * 4));
    __half* Yh    = (__half*)(w + alloc((size_t)N * 128 * 2));
    float* Y40    = (float*)(w + alloc((size_t)N * 40 * 4));
    float* H      = (float*)(w + alloc((size_t)N * 128 * 4));
    float* p1s = stats;
    float* p1q = stats + NPART * 128;
    float* p2s = stats + 2 * NPART * 128;
    float* p2q = stats + 3 * NPART * 128;

    hipMemsetAsync(cnt, 0, (size_t)N * 4, stream);
    hipMemsetAsync(stats, 0, (size_t)4 * NPART * 128 * 4, stream);

    hist_k<<<(E + 255) / 256, 256, 0, stream>>>(edst, cnt, E);
    int nb = (N + 2047) / 2048;
    scan1_k<<<nb, 1024, 0, stream>>>(cnt, rowptr, bsum, N);
    scan2_k<<<1, 64, 0, stream>>>(bsum, nb);
    scan3_k<<<(N + 255) / 256, 256, 0, stream>>>(rowptr, cursor, bsum, N);
    fill_k<<<(E + 255) / 256, 256, 0, stream>>>(esrc, edst, ew, cursor, epair, E);

    int gb128 = (N + 127) / 128;
    int gb64 = (N + 63) / 64;
    int sb = (N + 3) / 4;

    gemm128_k<<<gb128, 256, 0, stream>>>(feat, W1, Yh, N, nullptr, nullptr);
    spmm128_k<<<sb, 256, 0, stream>>>(rowptr, epair, Yh, H, N, p1s, p1q);
    bnstats_k<<<1, 128, 0, stream>>>(p1s, p1q, g1, be1, sc1, sh1, N);

    gemm128_k<<<gb128, 256, 0, stream>>>(H, W2, Yh, N, sc1, sh1);
    spmm128_k<<<sb, 256, 0, stream>>>(rowptr, epair, Yh, H, N, p2s, p2q);
    bnstats_k<<<1, 128, 0, stream>>>(p2s, p2q, g2, be2, sc2, sh2, N);

    gemm40_k<<<gb64, 256, 0, stream>>>(H, W3, Y40, N, sc2, sh2);
    spmm40_k<<<sb, 256, 0, stream>>>(rowptr, epair, Y40, out, N, b3);
}